// Round 2
// baseline (68835.718 us; speedup 1.0000x reference)
//
#include <hip/hip_runtime.h>
#include <math.h>

// Persistent cooperative-style RK45 (Dormand-Prince) integrator for
//   dy/dt = y * (r + A@y + eps@P[d(t)]),  n=4096, up to 512 adaptive steps.
// One kernel launch; grid-wide barriers via device-scope atomics (all 256
// blocks co-resident: ~33KB LDS -> >=4 blocks/CU capacity, grid == #CUs).
//
// R1 fix: mv() now covers all 4096 columns (4 chunks of 256 threads x float4);
// R0 version covered only 1024 columns -> lost diagonal damping -> 1e38 blowup.

#define N        4096
#define NBLK     256
#define NTHR     256
#define ROWS     16          // rows of A per block (NBLK*ROWS == N)
#define MAXSTEP  512
#define PERTS    8

static_assert(NBLK * ROWS == N, "row partition");
static_assert(NTHR * 16 == N, "elementwise partition (4 float4 per thread)");

__device__ __forceinline__ float4 ld4(const float* p){ return *reinterpret_cast<const float4*>(p); }
__device__ __forceinline__ void   st4(float* p, float4 v){ *reinterpret_cast<float4*>(p) = v; }

__device__ __forceinline__ void gridbar(unsigned* cnt, unsigned* gen){
  __syncthreads();
  if (threadIdx.x == 0){
    __threadfence();   // release: make prior global writes visible device-wide
    unsigned g = __hip_atomic_load(gen, __ATOMIC_RELAXED, __HIP_MEMORY_SCOPE_AGENT);
    unsigned a = __hip_atomic_fetch_add(cnt, 1u, __ATOMIC_RELAXED, __HIP_MEMORY_SCOPE_AGENT);
    if (a == (unsigned)(NBLK - 1)){
      __threadfence(); // order arrivals (and cnt reset) before generation release
      __hip_atomic_store(cnt, 0u, __ATOMIC_RELAXED, __HIP_MEMORY_SCOPE_AGENT);
      __hip_atomic_fetch_add(gen, 1u, __ATOMIC_RELEASE, __HIP_MEMORY_SCOPE_AGENT);
    } else {
      while (__hip_atomic_load(gen, __ATOMIC_RELAXED, __HIP_MEMORY_SCOPE_AGENT) == g)
        __builtin_amdgcn_s_sleep(2);
    }
    __threadfence();   // acquire: invalidate stale local caches
  }
  __syncthreads();
}

__global__ void __launch_bounds__(NTHR)
mbpert_rk45_kernel(const float* __restrict__ x, const int* __restrict__ tptr,
                   const float* __restrict__ r, const float* __restrict__ A,
                   const float* __restrict__ eps, const float* __restrict__ Pm,
                   float* __restrict__ out, float* __restrict__ W, int Tm)
{
  __shared__ float ys[N];              // full stage vector y_s  (16 KB)
  __shared__ float part[ROWS * NTHR];  // matvec partials        (16 KB)
  __shared__ float dot_sh[ROWS];
  __shared__ float r_sh[ROWS];
  __shared__ float eps_sh[ROWS * PERTS];
  __shared__ float P_sh[32 * PERTS];
  __shared__ float yeff_sh[ROWS];
  __shared__ float red_sh[ROWS];

  const int tid = threadIdx.x;
  const int b   = blockIdx.x;
  const int rowbase = b * ROWS;
  const int lane = tid & 63;
  const int wv   = tid >> 6;

  // workspace layout (floats)
  unsigned* cnt = reinterpret_cast<unsigned*>(W);
  unsigned* gen = reinterpret_cast<unsigned*>(W) + 1;
  float* err_sum = W + 64;             // [MAXSTEP], pre-zeroed by memset
  float* y5g   = W + 1024;
  float* k1 = W + 1024 + N * 1;
  float* k2 = W + 1024 + N * 2;
  float* k3 = W + 1024 + N * 3;
  float* k4 = W + 1024 + N * 4;
  float* k5 = W + 1024 + N * 5;
  float* k6 = W + 1024 + N * 6;
  float* base0 = W + 1024 + N * 7;
  float* base1 = W + 1024 + N * 8;

  // persistent per-block LDS: r / eps slices for our rows, full P table
  if (tid < ROWS)         r_sh[tid]   = r[rowbase + tid];
  if (tid < ROWS * PERTS) eps_sh[tid] = eps[rowbase * PERTS + tid];
  if (tid < (Tm + 1) * PERTS) P_sh[tid] = Pm[tid];
  __syncthreads();

  const float t_end = (float)(*tptr);
  const float Tf    = (float)Tm;
  float t = 0.0f;
  float h = t_end * 0.01f;

  // matvec: our 16 rows of A times ys (LDS, full 4096) -> dot_sh[0..15]
  auto mv = [&](){
    float acc[ROWS];
    #pragma unroll
    for (int rr = 0; rr < ROWS; rr++) acc[rr] = 0.0f;
    #pragma unroll
    for (int q = 0; q < 4; q++){
      const int c = (q * NTHR + tid) * 4;          // columns c..c+3
      float4 yv = ld4(ys + c);
      const float* Ab = A + (size_t)rowbase * N + c;
      #pragma unroll
      for (int rr = 0; rr < ROWS; rr++){           // 16 independent dwordx4 loads
        float4 a = ld4(Ab + (size_t)rr * N);
        acc[rr] = fmaf(a.x, yv.x, fmaf(a.y, yv.y, fmaf(a.z, yv.z, fmaf(a.w, yv.w, acc[rr]))));
      }
    }
    #pragma unroll
    for (int rr = 0; rr < ROWS; rr++) part[rr * NTHR + tid] = acc[rr];
    __syncthreads();
    #pragma unroll
    for (int rr = 0; rr < 4; rr++){                // wave wv reduces rows 4wv..4wv+3
      int row = wv * 4 + rr;
      const float* pr = part + row * NTHR;
      float s = pr[lane] + pr[lane + 64] + pr[lane + 128] + pr[lane + 192];
      #pragma unroll
      for (int off = 32; off; off >>= 1) s += __shfl_xor(s, off, 64);
      if (lane == 0) dot_sh[row] = s;
    }
    __syncthreads();
  };

  // k value for row `tid` (call with tid<ROWS): y_s * (r + A@y_s + eps@P[d])
  auto kval = [&](float ts) -> float {
    int d = (int)((Tf * ts) / 30.0f);
    d = d < 0 ? 0 : (d > Tm ? Tm : d);
    float ep = 0.f;
    #pragma unroll
    for (int p = 0; p < PERTS; p++) ep += eps_sh[tid * PERTS + p] * P_sh[d * PERTS + p];
    return ys[rowbase + tid] * (r_sh[tid] + dot_sh[tid] + ep);
  };

  // ys = base + h * sum(cf[m]*kp[m]); trailing syncthreads
  auto build = [&](const float* base, const float* const* kp, const float* cf, int nk){
    #pragma unroll
    for (int q = 0; q < 4; q++){
      int f = (q * NTHR + tid) * 4;
      float4 v = ld4(base + f);
      for (int m = 0; m < nk; m++){
        float c = h * cf[m];
        float4 kv = ld4(kp[m] + f);
        v.x = fmaf(c, kv.x, v.x); v.y = fmaf(c, kv.y, v.y);
        v.z = fmaf(c, kv.z, v.z); v.w = fmaf(c, kv.w, v.w);
      }
      st4(ys + f, v);
    }
    __syncthreads();
  };

  const float* base_prev = x;
  const float* srcy = x;
  bool exhausted = true;

  for (int n = 0; n < MAXSTEP; ++n){
    bool accept = false;
    if (n > 0){
      float es = err_sum[n - 1];                       // visible after stage-7 barrier
      float enorm = sqrtf(es * (1.0f / (float)N));
      accept = (enorm <= 1.0f);
      if (accept) t += h;
      float fac = 0.9f * powf(enorm + 1e-10f, -0.2f);
      fac = fminf(fmaxf(fac, 0.2f), 10.0f);
      h *= fac;
      srcy = accept ? (const float*)y5g : base_prev;
    }
    if (t >= t_end) { exhausted = false; break; }      // integration finished
    h = fminf(h, t_end - t);
    if (!(h > 0.0f)) { exhausted = false; break; }     // frozen (h==0) -> state fixed
    float* base_cur = (n & 1) ? base1 : base0;

    // ---- stage 1: ys = y_eff; publish our slice of y_eff ----
    #pragma unroll
    for (int q = 0; q < 4; q++){ int f = (q * NTHR + tid) * 4; st4(ys + f, ld4(srcy + f)); }
    __syncthreads();
    if (tid < ROWS){ float v = ys[rowbase + tid]; yeff_sh[tid] = v; base_cur[rowbase + tid] = v; }
    mv();
    if (tid < ROWS) k1[rowbase + tid] = kval(t);
    gridbar(cnt, gen);

    // ---- stage 2 ----
    { const float cf[1] = {0.2f}; const float* kp[1] = {k1};
      build(base_cur, kp, cf, 1); mv();
      if (tid < ROWS) k2[rowbase + tid] = kval(t + 0.2f * h);
      gridbar(cnt, gen); }

    // ---- stage 3 ----
    { const float cf[2] = {3.f/40.f, 9.f/40.f}; const float* kp[2] = {k1, k2};
      build(base_cur, kp, cf, 2); mv();
      if (tid < ROWS) k3[rowbase + tid] = kval(t + 0.3f * h);
      gridbar(cnt, gen); }

    // ---- stage 4 ----
    { const float cf[3] = {44.f/45.f, -56.f/15.f, 32.f/9.f}; const float* kp[3] = {k1, k2, k3};
      build(base_cur, kp, cf, 3); mv();
      if (tid < ROWS) k4[rowbase + tid] = kval(t + 0.8f * h);
      gridbar(cnt, gen); }

    // ---- stage 5 ----
    { const float cf[4] = {19372.f/6561.f, -25360.f/2187.f, 64448.f/6561.f, -212.f/729.f};
      const float* kp[4] = {k1, k2, k3, k4};
      build(base_cur, kp, cf, 4); mv();
      if (tid < ROWS) k5[rowbase + tid] = kval(t + (8.f/9.f) * h);
      gridbar(cnt, gen); }

    // ---- stage 6 ----
    { const float cf[5] = {9017.f/3168.f, -355.f/33.f, 46732.f/5247.f, 49.f/176.f, -5103.f/18656.f};
      const float* kp[5] = {k1, k2, k3, k4, k5};
      build(base_cur, kp, cf, 5); mv();
      if (tid < ROWS) k6[rowbase + tid] = kval(t + h);
      gridbar(cnt, gen); }

    // ---- stage 7: ys = y5 candidate; k7 stays local; err partial ----
    { const float cf[5] = {35.f/384.f, 500.f/1113.f, 125.f/192.f, -2187.f/6784.f, 11.f/84.f};
      const float* kp[5] = {k1, k3, k4, k5, k6};
      build(base_cur, kp, cf, 5);                       // ys == y5
      if (tid < ROWS) y5g[rowbase + tid] = ys[rowbase + tid];
      mv();
      if (tid < ROWS){
        float k7v = kval(t + h);
        int gi = rowbase + tid;
        float e = (71.f/57600.f)  * k1[gi] - (71.f/16695.f)    * k3[gi]
                + (71.f/1920.f)   * k4[gi] - (17253.f/339200.f)* k5[gi]
                + (22.f/525.f)    * k6[gi] - (1.f/40.f)        * k7v;
        e *= h;
        float y5v = ys[gi];
        float sc = 1e-6f + 1e-3f * fmaxf(fabsf(yeff_sh[tid]), fabsf(y5v));
        float q = e / sc;
        red_sh[tid] = q * q;
      }
      __syncthreads();
      if (tid == 0){
        float s = 0.f;
        #pragma unroll
        for (int i = 0; i < ROWS; i++) s += red_sh[i];
        atomicAdd(&err_sum[n], s);
      }
      gridbar(cnt, gen);
    }
    base_prev = base_cur;
  }

  if (exhausted){
    // apply the final (iteration 511) accept decision, as the reference does
    float es = err_sum[MAXSTEP - 1];
    bool accept = sqrtf(es * (1.0f / (float)N)) <= 1.0f;
    srcy = accept ? (const float*)y5g : base_prev;
  }
  if (tid < ROWS) out[rowbase + tid] = srcy[rowbase + tid];
}

extern "C" void kernel_launch(void* const* d_in, const int* in_sizes, int n_in,
                              void* d_out, int out_size, void* d_ws, size_t ws_size,
                              hipStream_t stream)
{
  const float* x   = (const float*)d_in[0];
  const int*   tp  = (const int*)  d_in[1];
  const float* r   = (const float*)d_in[2];
  const float* A   = (const float*)d_in[3];
  const float* eps = (const float*)d_in[4];
  const float* Pm  = (const float*)d_in[5];
  float* out = (float*)d_out;
  float* W   = (float*)d_ws;
  int Tm = in_sizes[5] / PERTS - 1;   // P rows - 1  (== 30)

  // zero barrier state + err_sum accumulators (ws is poisoned before each call)
  hipMemsetAsync(d_ws, 0, 4096, stream);
  mbpert_rk45_kernel<<<dim3(NBLK), dim3(NTHR), 0, stream>>>(
      x, tp, r, A, eps, Pm, out, W, Tm);
}

// Round 3
// 39447.156 us; speedup vs baseline: 1.7450x; 1.7450x over previous
//
#include <hip/hip_runtime.h>
#include <math.h>

// Persistent RK45 (Dormand-Prince, FSAL) integrator for
//   dy/dt = y * (r + A@y + eps@P[d(t)]),  n=4096, up to 512 adaptive steps.
// R3: hierarchical monotonic grid barrier (8 arrival lines + 8 broadcast
// lines -> no 256-way same-line contention), atomic-free err exchange
// (per-block slots + redundant deterministic reduce), FSAL (k1 := k7 on
// accept -> 6 stages/step), base vector cached in LDS (no global y arrays).

#define N        4096
#define NBLK     256
#define NTHR     256
#define ROWS     16          // rows of A per block (NBLK*ROWS == N)
#define MAXSTEP  512
#define PERTS    8

static_assert(NBLK * ROWS == N, "row partition");
static_assert(NTHR * 16 == N, "elementwise partition (4 float4 per thread)");

__device__ __forceinline__ float4 ld4(const float* p){ return *reinterpret_cast<const float4*>(p); }
__device__ __forceinline__ void   st4(float* p, float4 v){ *reinterpret_cast<float4*>(p) = v; }

// Hierarchical grid barrier. Wi layout (unsigned words):
//   [g*64]        g=0..7  per-group monotonic arrival counters (256B apart)
//   [512]                 global group-arrival counter
//   [576 + g*64]  g=0..7  per-group generation broadcast lines
__device__ __forceinline__ void gridbar(unsigned* Wi, unsigned bar_gen, int b){
  __syncthreads();
  if (threadIdx.x == 0){
    __threadfence();   // release: flush this block's k/err stores to coherence point
    const int g = b & 7;
    unsigned* xc = Wi + (size_t)g * 64;
    unsigned* gc = Wi + 512;
    unsigned* bc = Wi + 576 + (size_t)g * 64;
    unsigned a = __hip_atomic_fetch_add(xc, 1u, __ATOMIC_RELAXED, __HIP_MEMORY_SCOPE_AGENT);
    if (a == bar_gen * 32u - 1u){                       // last of my 32-block group
      unsigned ga = __hip_atomic_fetch_add(gc, 1u, __ATOMIC_RELAXED, __HIP_MEMORY_SCOPE_AGENT);
      if (ga == bar_gen * 8u - 1u){                     // last group -> broadcast
        #pragma unroll
        for (int i = 0; i < 8; i++)
          __hip_atomic_store(Wi + 576 + (size_t)i * 64, bar_gen,
                             __ATOMIC_RELAXED, __HIP_MEMORY_SCOPE_AGENT);
      }
    }
    while (__hip_atomic_load(bc, __ATOMIC_RELAXED, __HIP_MEMORY_SCOPE_AGENT) < bar_gen)
      __builtin_amdgcn_s_sleep(8);
    __threadfence();   // acquire: invalidate stale L1/L2 before reading peers' data
  }
  __syncthreads();
}

__global__ void __launch_bounds__(NTHR)
mbpert_rk45_kernel(const float* __restrict__ x, const int* __restrict__ tptr,
                   const float* __restrict__ r, const float* __restrict__ A,
                   const float* __restrict__ eps, const float* __restrict__ Pm,
                   float* __restrict__ out, float* __restrict__ W, int Tm)
{
  __shared__ float ys[N];              // stage vector            (16 KB)
  __shared__ float ysb[N];             // current base vector     (16 KB)
  __shared__ float part[ROWS * NTHR];  // matvec partials         (16 KB)
  __shared__ float dot_sh[ROWS];
  __shared__ float r_sh[ROWS];
  __shared__ float eps_sh[ROWS * PERTS];
  __shared__ float P_sh[32 * PERTS];
  __shared__ float red_sh[ROWS];
  __shared__ float es_sh;

  const int tid = threadIdx.x;
  const int b   = blockIdx.x;
  const int rowbase = b * ROWS;
  const int lane = tid & 63;
  const int wv   = tid >> 6;

  unsigned* Wi = reinterpret_cast<unsigned*>(W);
  float* err_part = W + 1088;          // [NBLK] per-block err partials
  float* Wd = W + 2048;                // data region: 7 k-arrays
  float* kb[7];
  #pragma unroll
  for (int i = 0; i < 7; i++) kb[i] = Wd + (size_t)i * N;

  // persistent per-block LDS: r / eps slices for our rows, full P table
  if (tid < ROWS)         r_sh[tid]   = r[rowbase + tid];
  if (tid < ROWS * PERTS) eps_sh[tid] = eps[rowbase * PERTS + tid];
  if (tid < (Tm + 1) * PERTS) P_sh[tid] = Pm[tid];
  // base <- x
  #pragma unroll
  for (int q = 0; q < 4; q++){ int f = (q * NTHR + tid) * 4; st4(ysb + f, ld4(x + f)); }
  __syncthreads();

  const float t_end = (float)(*tptr);
  const float Tf    = (float)Tm;
  float t = 0.0f;
  float h = t_end * 0.01f;
  unsigned bg = 0;                     // barrier generation (identical in all blocks)

  // matvec: our 16 rows of A times ys (LDS, full 4096) -> dot_sh[0..15]
  auto mv = [&](){
    float acc[ROWS];
    #pragma unroll
    for (int rr = 0; rr < ROWS; rr++) acc[rr] = 0.0f;
    #pragma unroll
    for (int q = 0; q < 4; q++){
      const int c = (q * NTHR + tid) * 4;          // columns c..c+3
      float4 yv = ld4(ys + c);
      const float* Ab = A + (size_t)rowbase * N + c;
      #pragma unroll
      for (int rr = 0; rr < ROWS; rr++){           // 16 independent dwordx4 loads
        float4 a = ld4(Ab + (size_t)rr * N);
        acc[rr] = fmaf(a.x, yv.x, fmaf(a.y, yv.y, fmaf(a.z, yv.z, fmaf(a.w, yv.w, acc[rr]))));
      }
    }
    #pragma unroll
    for (int rr = 0; rr < ROWS; rr++) part[rr * NTHR + tid] = acc[rr];
    __syncthreads();
    #pragma unroll
    for (int rr = 0; rr < 4; rr++){                // wave wv reduces rows 4wv..4wv+3
      int row = wv * 4 + rr;
      const float* pr = part + row * NTHR;
      float s = pr[lane] + pr[lane + 64] + pr[lane + 128] + pr[lane + 192];
      #pragma unroll
      for (int off = 32; off; off >>= 1) s += __shfl_xor(s, off, 64);
      if (lane == 0) dot_sh[row] = s;
    }
    __syncthreads();
  };

  // k value for row `tid` (call with tid<ROWS): y_s * (r + A@y_s + eps@P[d])
  auto kval = [&](float ts) -> float {
    int d = (int)((Tf * ts) / 30.0f);
    d = d < 0 ? 0 : (d > Tm ? Tm : d);
    float ep = 0.f;
    #pragma unroll
    for (int p = 0; p < PERTS; p++) ep += eps_sh[tid * PERTS + p] * P_sh[d * PERTS + p];
    return ys[rowbase + tid] * (r_sh[tid] + dot_sh[tid] + ep);
  };

  // ys = ysb + h * sum(cf[m]*kp[m]);  base from LDS, k's from global
  auto build = [&](const float* const* kp, const float* cf, int nk){
    #pragma unroll
    for (int q = 0; q < 4; q++){
      int f = (q * NTHR + tid) * 4;
      float4 v = ld4(ysb + f);
      for (int m = 0; m < nk; m++){
        float c = h * cf[m];
        float4 kv = ld4(kp[m] + f);
        v.x = fmaf(c, kv.x, v.x); v.y = fmaf(c, kv.y, v.y);
        v.z = fmaf(c, kv.z, v.z); v.w = fmaf(c, kv.w, v.w);
      }
      st4(ys + f, v);
    }
    __syncthreads();
  };

  // deterministic redundant reduce of the 256 per-block err partials
  auto read_err = [&]() -> float {
    if (tid < 64){
      float e = err_part[tid] + err_part[tid + 64] + err_part[tid + 128] + err_part[tid + 192];
      #pragma unroll
      for (int off = 32; off; off >>= 1) e += __shfl_xor(e, off, 64);
      if (tid == 0) es_sh = e;
    }
    __syncthreads();
    float v = es_sh;
    __syncthreads();
    return v;
  };

  bool exhausted = true;

  for (int n = 0; n < MAXSTEP; ++n){
    if (n > 0){
      float es = read_err();                           // err of step n-1
      float enorm = sqrtf(es * (1.0f / (float)N));
      bool accept = (enorm <= 1.0f);
      if (accept){
        t += h;
        float* tmp = kb[0]; kb[0] = kb[6]; kb[6] = tmp;   // FSAL: k1 <- k7
        #pragma unroll
        for (int q = 0; q < 4; q++){ int f = (q * NTHR + tid) * 4; st4(ysb + f, ld4(ys + f)); }
      }
      __syncthreads();
      float fac = 0.9f * powf(enorm + 1e-10f, -0.2f);
      fac = fminf(fmaxf(fac, 0.2f), 10.0f);
      h *= fac;
    }
    if (t >= t_end) { exhausted = false; break; }      // integration finished
    h = fminf(h, t_end - t);
    if (!(h > 0.0f)) { exhausted = false; break; }     // frozen -> state fixed

    if (n == 0){
      // ---- stage 1 (only ever once: FSAL covers all later steps) ----
      #pragma unroll
      for (int q = 0; q < 4; q++){ int f = (q * NTHR + tid) * 4; st4(ys + f, ld4(ysb + f)); }
      __syncthreads();
      mv();
      if (tid < ROWS) kb[0][rowbase + tid] = kval(t);
      ++bg; gridbar(Wi, bg, b);
    }

    // ---- stage 2 ----
    { const float cf[1] = {0.2f}; const float* kp[1] = {kb[0]};
      build(kp, cf, 1); mv();
      if (tid < ROWS) kb[1][rowbase + tid] = kval(t + 0.2f * h);
      ++bg; gridbar(Wi, bg, b); }

    // ---- stage 3 ----
    { const float cf[2] = {3.f/40.f, 9.f/40.f}; const float* kp[2] = {kb[0], kb[1]};
      build(kp, cf, 2); mv();
      if (tid < ROWS) kb[2][rowbase + tid] = kval(t + 0.3f * h);
      ++bg; gridbar(Wi, bg, b); }

    // ---- stage 4 ----
    { const float cf[3] = {44.f/45.f, -56.f/15.f, 32.f/9.f};
      const float* kp[3] = {kb[0], kb[1], kb[2]};
      build(kp, cf, 3); mv();
      if (tid < ROWS) kb[3][rowbase + tid] = kval(t + 0.8f * h);
      ++bg; gridbar(Wi, bg, b); }

    // ---- stage 5 ----
    { const float cf[4] = {19372.f/6561.f, -25360.f/2187.f, 64448.f/6561.f, -212.f/729.f};
      const float* kp[4] = {kb[0], kb[1], kb[2], kb[3]};
      build(kp, cf, 4); mv();
      if (tid < ROWS) kb[4][rowbase + tid] = kval(t + (8.f/9.f) * h);
      ++bg; gridbar(Wi, bg, b); }

    // ---- stage 6 ----
    { const float cf[5] = {9017.f/3168.f, -355.f/33.f, 46732.f/5247.f, 49.f/176.f, -5103.f/18656.f};
      const float* kp[5] = {kb[0], kb[1], kb[2], kb[3], kb[4]};
      build(kp, cf, 5); mv();
      if (tid < ROWS) kb[5][rowbase + tid] = kval(t + h);
      ++bg; gridbar(Wi, bg, b); }

    // ---- stage 7: ys = y5 candidate; k7 -> kb[6]; err partial ----
    { const float cf[5] = {35.f/384.f, 500.f/1113.f, 125.f/192.f, -2187.f/6784.f, 11.f/84.f};
      const float* kp[5] = {kb[0], kb[2], kb[3], kb[4], kb[5]};
      build(kp, cf, 5);                                // ys == y5 candidate
      mv();
      if (tid < ROWS){
        float k7v = kval(t + h);
        int gi = rowbase + tid;
        kb[6][gi] = k7v;                               // FSAL source
        float e = (71.f/57600.f)  * kb[0][gi] - (71.f/16695.f)    * kb[2][gi]
                + (71.f/1920.f)   * kb[3][gi] - (17253.f/339200.f)* kb[4][gi]
                + (22.f/525.f)    * kb[5][gi] - (1.f/40.f)        * k7v;
        e *= h;
        float sc = 1e-6f + 1e-3f * fmaxf(fabsf(ysb[gi]), fabsf(ys[gi]));
        float q = e / sc;
        red_sh[tid] = q * q;
      }
      __syncthreads();
      if (tid == 0){
        float s = 0.f;
        #pragma unroll
        for (int i = 0; i < ROWS; i++) s += red_sh[i];
        err_part[b] = s;                               // own slot, no atomics
      }
      ++bg; gridbar(Wi, bg, b);
    }
  }

  if (exhausted){
    // apply the final (iteration 511) accept decision, as the reference does
    float es = read_err();
    bool accept = sqrtf(es * (1.0f / (float)N)) <= 1.0f;
    if (tid < ROWS) out[rowbase + tid] = accept ? ys[rowbase + tid] : ysb[rowbase + tid];
  } else {
    if (tid < ROWS) out[rowbase + tid] = ysb[rowbase + tid];
  }
}

extern "C" void kernel_launch(void* const* d_in, const int* in_sizes, int n_in,
                              void* d_out, int out_size, void* d_ws, size_t ws_size,
                              hipStream_t stream)
{
  const float* x   = (const float*)d_in[0];
  const int*   tp  = (const int*)  d_in[1];
  const float* r   = (const float*)d_in[2];
  const float* A   = (const float*)d_in[3];
  const float* eps = (const float*)d_in[4];
  const float* Pm  = (const float*)d_in[5];
  float* out = (float*)d_out;
  float* W   = (float*)d_ws;
  int Tm = in_sizes[5] / PERTS - 1;   // P rows - 1  (== 30)

  // zero barrier counters + broadcast lines + err slots (ws re-poisoned per call)
  hipMemsetAsync(d_ws, 0, 8192, stream);
  mbpert_rk45_kernel<<<dim3(NBLK), dim3(NTHR), 0, stream>>>(
      x, tp, r, A, eps, Pm, out, W, Tm);
}

// Round 4
// 25232.184 us; speedup vs baseline: 2.7281x; 1.5634x over previous
//
#include <hip/hip_runtime.h>
#include <hip/hip_fp16.h>
#include <math.h>

// Persistent RK45 (Dormand-Prince, FSAL) integrator for
//   dy/dt = y * (r + A@y + eps@P[d(t)]),  n=4096, up to 512 adaptive steps.
// R4: A held PERMANENTLY in registers as fp16 (128 half2/thread, 1 block/CU,
// 256 blocks x 256 thr) -> zero per-stage A traffic (R3 counter analysis:
// 55us/stage == 64MB A refetch at 1.2 TB/s; fences + 8MB/XCD working set
// make A un-cacheable in L2). k-history in LDS (6 x 16KB, k7 reuses k2 slot).
// Per-stage cross-block exchange = 16 floats out / 16KB in per block.
// Decentralized flag barrier: own-flag store + all-flags poll (no RMW chain).

#define N        4096
#define NBLK     256
#define NTHR     256
#define ROWS     16          // rows of A per block (NBLK*ROWS == N)
#define MAXSTEP  512
#define PERTS    8

static_assert(NBLK * ROWS == N, "row partition");
static_assert(NTHR * 16 == N, "column partition (4 float4 per thread)");

__device__ __forceinline__ float4 ld4(const float* p){ return *reinterpret_cast<const float4*>(p); }
__device__ __forceinline__ void   st4(float* p, float4 v){ *reinterpret_cast<float4*>(p) = v; }

// Decentralized flag barrier: block stores flags[b]=gen (after release fence),
// then all 256 threads poll all 256 flags until everyone reached gen.
__device__ __forceinline__ void gridbar(unsigned* flags, unsigned gen){
  __syncthreads();
  if (threadIdx.x == 0){
    __threadfence();   // release: k/err stores visible device-wide
    __hip_atomic_store(&flags[blockIdx.x], gen, __ATOMIC_RELAXED, __HIP_MEMORY_SCOPE_AGENT);
  }
  for (;;){
    unsigned f = __hip_atomic_load(&flags[threadIdx.x], __ATOMIC_RELAXED, __HIP_MEMORY_SCOPE_AGENT);
    if (__syncthreads_count((int)(f >= gen)) == NTHR) break;
    __builtin_amdgcn_s_sleep(2);
  }
  if (threadIdx.x == 0) __threadfence();  // acquire: invalidate stale L1/L2
  __syncthreads();
}

__global__ void __launch_bounds__(NTHR, 1)
mbpert_rk45_kernel(const float* __restrict__ x, const int* __restrict__ tptr,
                   const float* __restrict__ r, const float* __restrict__ A,
                   const float* __restrict__ eps, const float* __restrict__ Pm,
                   float* __restrict__ out, float* __restrict__ W, int Tm)
{
  __shared__ float khist[6][N];        // 96 KB k-history (gfx950: 160KB LDS/WG)
  __shared__ float part_sm[ROWS * 4];  // per-wave matvec partials
  __shared__ float ys_rows[ROWS];      // stage vector at our 16 row indices
  __shared__ float ysb_rows[ROWS];     // base vector at our 16 row indices
  __shared__ float r_sh[ROWS];
  __shared__ float eps_sh[ROWS * PERTS];
  __shared__ float P_sh[32 * PERTS];
  __shared__ float epr_sh[ROWS];
  __shared__ float es_sh;

  const int tid = threadIdx.x;
  const int b   = blockIdx.x;
  const int rowbase = b * ROWS;
  const int lane = tid & 63;
  const int wv   = tid >> 6;

  unsigned* flags  = reinterpret_cast<unsigned*>(W);   // [256]
  float* err_part  = W + 256;                          // [256]
  float* kx0       = W + 1024;                         // [N] exchange buf A
  float* kx1       = W + 1024 + N;                     // [N] exchange buf B

  // ---- persistent LDS constants ----
  if (tid < ROWS)             r_sh[tid]   = r[rowbase + tid];
  if (tid < ROWS * PERTS)     eps_sh[tid] = eps[rowbase * PERTS + tid];
  if (tid < (Tm + 1) * PERTS) P_sh[tid]   = Pm[tid];
  if (tid < ROWS)             ysb_rows[tid] = x[rowbase + tid];

  // ---- A fragment -> registers (fp16), once ----
  // Thread owns cols (q*256+tid)*4..+3 (q=0..3) of rows rowbase..rowbase+15.
  __half2 Af[ROWS][8];
  #pragma unroll
  for (int rr = 0; rr < ROWS; rr++){
    const float* Ar = A + (size_t)(rowbase + rr) * N;
    #pragma unroll
    for (int q = 0; q < 4; q++){
      int c = (q * NTHR + tid) * 4;
      float4 a = ld4(Ar + c);
      Af[rr][2*q]   = __floats2half2_rn(a.x, a.y);
      Af[rr][2*q+1] = __floats2half2_rn(a.z, a.w);
    }
  }

  float4 ysbf[4], ysf[4];              // base / stage vector fragments (fp32)
  #pragma unroll
  for (int q = 0; q < 4; q++) ysbf[q] = ld4(x + (q * NTHR + tid) * 4);
  __syncthreads();

  const float t_end = (float)(*tptr);
  const float Tf    = (float)Tm;
  float t = 0.0f;
  float h = t_end * 0.01f;
  unsigned gen = 0;

  // matvec from registers: acc over our 16 cols, wave-reduce, park in part_sm
  auto mv = [&](){
    float acc[ROWS];
    #pragma unroll
    for (int rr = 0; rr < ROWS; rr++) acc[rr] = 0.0f;
    #pragma unroll
    for (int q = 0; q < 4; q++){
      float4 y = ysf[q];
      #pragma unroll
      for (int rr = 0; rr < ROWS; rr++){
        float2 lo = __half22float2(Af[rr][2*q]);
        float2 hi = __half22float2(Af[rr][2*q+1]);
        acc[rr] = fmaf(lo.x, y.x, fmaf(lo.y, y.y, fmaf(hi.x, y.z, fmaf(hi.y, y.w, acc[rr]))));
      }
    }
    __syncthreads();                   // part_sm free from previous stage
    #pragma unroll
    for (int rr = 0; rr < ROWS; rr++){
      float s = acc[rr];
      #pragma unroll
      for (int off = 32; off; off >>= 1) s += __shfl_xor(s, off, 64);
      if (lane == 0) part_sm[rr * 4 + wv] = s;
    }
    __syncthreads();
  };

  // k for row `tid` (tid<ROWS): y_s * (r + A@y_s + eps@P[d])
  auto kval = [&](float ts) -> float {
    int d = (int)((Tf * ts) / 30.0f);
    d = d < 0 ? 0 : (d > Tm ? Tm : d);
    float dot = part_sm[tid*4] + part_sm[tid*4+1] + part_sm[tid*4+2] + part_sm[tid*4+3];
    float ep = 0.f;
    #pragma unroll
    for (int p = 0; p < PERTS; p++) ep += eps_sh[tid * PERTS + p] * P_sh[d * PERTS + p];
    return ys_rows[tid] * (r_sh[tid] + dot + ep);
  };

  // ys = ysb + h * sum(cf[m] * khist[sli[m]]) over our 16 columns
  auto build = [&](const int* sli, const float* cf, int nk){
    #pragma unroll
    for (int q = 0; q < 4; q++){
      int c = (q * NTHR + tid) * 4;
      float4 v = ysbf[q];
      for (int m = 0; m < nk; m++){
        float cc = h * cf[m];
        float4 kv = ld4(&khist[sli[m]][c]);
        v.x = fmaf(cc, kv.x, v.x); v.y = fmaf(cc, kv.y, v.y);
        v.z = fmaf(cc, kv.z, v.z); v.w = fmaf(cc, kv.w, v.w);
      }
      ysf[q] = v;
      int o = c - rowbase;             // c,rowbase multiples of 4/16: full containment
      if (o >= 0 && o < ROWS) st4(&ys_rows[o], v);
    }
    __syncthreads();
  };

  // publish own 16 k's, barrier, pull full 4096-vector into khist[slot]
  auto exchange = [&](int slot, float kv){
    ++gen;
    float* kx = (gen & 1u) ? kx1 : kx0;          // double buffer by parity
    if (tid < ROWS) kx[rowbase + tid] = kv;
    gridbar(flags, gen);
    #pragma unroll
    for (int q = 0; q < 4; q++){
      int c = (q * NTHR + tid) * 4;
      st4(&khist[slot][c], ld4(kx + c));
    }
    __syncthreads();
  };

  // deterministic redundant reduce of the 256 per-block err partials
  auto read_err = [&]() -> float {
    if (tid < 64){
      float e = err_part[tid] + err_part[tid + 64] + err_part[tid + 128] + err_part[tid + 192];
      #pragma unroll
      for (int off = 32; off; off >>= 1) e += __shfl_xor(e, off, 64);
      if (tid == 0) es_sh = e;
    }
    __syncthreads();
    float v = es_sh;
    __syncthreads();
    return v;
  };

  int sl[6] = {0, 1, 2, 3, 4, 5};      // logical k1..k6 -> physical LDS slots
  bool exhausted = true;

  for (int n = 0; n < MAXSTEP; ++n){
    if (n > 0){
      float es = read_err();
      float enorm = sqrtf(es * (1.0f / (float)N));
      bool accept = (enorm <= 1.0f);
      if (accept){
        t += h;
        int tmp = sl[0]; sl[0] = sl[1]; sl[1] = tmp;  // FSAL: k1 <- k7 (in k2's slot)
        #pragma unroll
        for (int q = 0; q < 4; q++) ysbf[q] = ysf[q];
        if (tid < ROWS) ysb_rows[tid] = ys_rows[tid];
      }
      float fac = 0.9f * powf(enorm + 1e-10f, -0.2f);
      fac = fminf(fmaxf(fac, 0.2f), 10.0f);
      h *= fac;
      __syncthreads();
    }
    if (t >= t_end) { exhausted = false; break; }
    h = fminf(h, t_end - t);
    if (!(h > 0.0f)) { exhausted = false; break; }

    if (n == 0){
      // ---- stage 1 (once ever; FSAL covers later steps) ----
      #pragma unroll
      for (int q = 0; q < 4; q++){
        ysf[q] = ysbf[q];
        int c = (q * NTHR + tid) * 4, o = c - rowbase;
        if (o >= 0 && o < ROWS) st4(&ys_rows[o], ysf[q]);
      }
      __syncthreads();
      mv();
      float kv = (tid < ROWS) ? kval(t) : 0.f;
      exchange(sl[0], kv);
    }

    // ---- stage 2 ----
    { const float cf[1] = {0.2f}; const int s_[1] = {sl[0]};
      build(s_, cf, 1); mv();
      float kv = (tid < ROWS) ? kval(t + 0.2f * h) : 0.f;
      exchange(sl[1], kv); }

    // ---- stage 3 ----
    { const float cf[2] = {3.f/40.f, 9.f/40.f}; const int s_[2] = {sl[0], sl[1]};
      build(s_, cf, 2); mv();
      float kv = (tid < ROWS) ? kval(t + 0.3f * h) : 0.f;
      exchange(sl[2], kv); }

    // ---- stage 4 ----
    { const float cf[3] = {44.f/45.f, -56.f/15.f, 32.f/9.f};
      const int s_[3] = {sl[0], sl[1], sl[2]};
      build(s_, cf, 3); mv();
      float kv = (tid < ROWS) ? kval(t + 0.8f * h) : 0.f;
      exchange(sl[3], kv); }

    // ---- stage 5 ----
    { const float cf[4] = {19372.f/6561.f, -25360.f/2187.f, 64448.f/6561.f, -212.f/729.f};
      const int s_[4] = {sl[0], sl[1], sl[2], sl[3]};
      build(s_, cf, 4); mv();
      float kv = (tid < ROWS) ? kval(t + (8.f/9.f) * h) : 0.f;
      exchange(sl[4], kv); }

    // ---- stage 6 ----
    { const float cf[5] = {9017.f/3168.f, -355.f/33.f, 46732.f/5247.f, 49.f/176.f, -5103.f/18656.f};
      const int s_[5] = {sl[0], sl[1], sl[2], sl[3], sl[4]};
      build(s_, cf, 5); mv();
      float kv = (tid < ROWS) ? kval(t + h) : 0.f;
      exchange(sl[5], kv); }

    // ---- stage 7: ys = y5 candidate; err partial; k7 -> sl[1] (k2 dead) ----
    { const float cf[5] = {35.f/384.f, 500.f/1113.f, 125.f/192.f, -2187.f/6784.f, 11.f/84.f};
      const int s_[5] = {sl[0], sl[2], sl[3], sl[4], sl[5]};
      build(s_, cf, 5);                // ys == y5 candidate; ys_rows updated
      mv();
      float k7v = 0.f;
      if (tid < ROWS){
        k7v = kval(t + h);
        int gi = rowbase + tid;
        float e = (71.f/57600.f)  * khist[sl[0]][gi] - (71.f/16695.f)    * khist[sl[2]][gi]
                + (71.f/1920.f)   * khist[sl[3]][gi] - (17253.f/339200.f)* khist[sl[4]][gi]
                + (22.f/525.f)    * khist[sl[5]][gi] - (1.f/40.f)        * k7v;
        e *= h;
        float sc = 1e-6f + 1e-3f * fmaxf(fabsf(ysb_rows[tid]), fabsf(ys_rows[tid]));
        float q = e / sc;
        epr_sh[tid] = q * q;
      }
      __syncthreads();
      if (tid == 0){
        float s = 0.f;
        #pragma unroll
        for (int i = 0; i < ROWS; i++) s += epr_sh[i];
        err_part[b] = s;
      }
      exchange(sl[1], k7v);            // includes the stage barrier
    }
  }

  if (exhausted){
    // apply the final (iteration 511) accept decision, as the reference does
    float es = read_err();
    bool accept = sqrtf(es * (1.0f / (float)N)) <= 1.0f;
    if (tid < ROWS) out[rowbase + tid] = accept ? ys_rows[tid] : ysb_rows[tid];
  } else {
    if (tid < ROWS) out[rowbase + tid] = ysb_rows[tid];
  }
}

extern "C" void kernel_launch(void* const* d_in, const int* in_sizes, int n_in,
                              void* d_out, int out_size, void* d_ws, size_t ws_size,
                              hipStream_t stream)
{
  const float* x   = (const float*)d_in[0];
  const int*   tp  = (const int*)  d_in[1];
  const float* r   = (const float*)d_in[2];
  const float* A   = (const float*)d_in[3];
  const float* eps = (const float*)d_in[4];
  const float* Pm  = (const float*)d_in[5];
  float* out = (float*)d_out;
  float* W   = (float*)d_ws;
  int Tm = in_sizes[5] / PERTS - 1;   // P rows - 1  (== 30)

  // zero the barrier flag array (everything else is written before read)
  hipMemsetAsync(d_ws, 0, 1024, stream);
  mbpert_rk45_kernel<<<dim3(NBLK), dim3(NTHR), 0, stream>>>(
      x, tp, r, A, eps, Pm, out, W, Tm);
}

// Round 5
// 16739.243 us; speedup vs baseline: 4.1122x; 1.5074x over previous
//
#include <hip/hip_runtime.h>
#include <hip/hip_fp16.h>
#include <math.h>

// Persistent RK45 (Dormand-Prince, FSAL) integrator for
//   dy/dt = y * (r + A@y + eps@P[d(t)]),  n=4096, up to 512 adaptive steps.
// R5: FENCE-FREE grid barrier. R4 counter analysis: 35us/stage with ~0 HBM
// traffic and 6% VALU -> the __threadfence() pair (L2 writeback + L1/L2
// invalidate on non-coherent-XCD gfx950) was the cost (and caused R3's
// 64MB/stage A refetch). All cross-block data now moves via relaxed
// agent-scope atomics (which bypass L1/L2 to the coherence point -- proven
// coherent by R4's own flag poll); producer orders data-before-flag with a
// wave-local s_waitcnt(0). No cache-maintenance ops remain in the loop.
// A stays permanently in registers as fp16 (128 half2/thread, 1 block/CU).

#define N        4096
#define NBLK     256
#define NTHR     256
#define ROWS     16          // rows of A per block (NBLK*ROWS == N)
#define MAXSTEP  512
#define PERTS    8

typedef unsigned long long ull;

static_assert(NBLK * ROWS == N, "row partition");
static_assert(NTHR * 16 == N, "column partition (4 float4 per thread)");

__device__ __forceinline__ float4 ld4(const float* p){ return *reinterpret_cast<const float4*>(p); }
__device__ __forceinline__ void   st4(float* p, float4 v){ *reinterpret_cast<float4*>(p) = v; }

__global__ void __launch_bounds__(NTHR, 1)
mbpert_rk45_kernel(const float* __restrict__ x, const int* __restrict__ tptr,
                   const float* __restrict__ r, const float* __restrict__ A,
                   const float* __restrict__ eps, const float* __restrict__ Pm,
                   float* __restrict__ out, float* __restrict__ W, int Tm)
{
  __shared__ float khist[6][N];        // 96 KB k-history (gfx950: 160KB LDS/WG)
  __shared__ float part_sm[ROWS * 4];  // per-wave matvec partials
  __shared__ float ys_rows[ROWS];      // stage vector at our 16 row indices
  __shared__ float ysb_rows[ROWS];     // base vector at our 16 row indices
  __shared__ float r_sh[ROWS];
  __shared__ float eps_sh[ROWS * PERTS];
  __shared__ float P_sh[32 * PERTS];
  __shared__ float epr_sh[ROWS];
  __shared__ float es_sh;

  const int tid = threadIdx.x;
  const int b   = blockIdx.x;
  const int rowbase = b * ROWS;
  const int lane = tid & 63;
  const int wv   = tid >> 6;

  unsigned* flags    = reinterpret_cast<unsigned*>(W);   // [256] barrier flags
  float*    err_part = W + 256;                          // [256] err partials (atomic access)
  ull*      kx0u     = reinterpret_cast<ull*>(W + 1024);       // [N/2] exchange buf A
  ull*      kx1u     = reinterpret_cast<ull*>(W + 1024 + N);   // [N/2] exchange buf B

  // ---- persistent LDS constants ----
  if (tid < ROWS)             r_sh[tid]   = r[rowbase + tid];
  if (tid < ROWS * PERTS)     eps_sh[tid] = eps[rowbase * PERTS + tid];
  if (tid < (Tm + 1) * PERTS) P_sh[tid]   = Pm[tid];
  if (tid < ROWS)             ysb_rows[tid] = x[rowbase + tid];

  // ---- A fragment -> registers (fp16), once ----
  // Thread owns cols (q*256+tid)*4..+3 (q=0..3) of rows rowbase..rowbase+15.
  __half2 Af[ROWS][8];
  #pragma unroll
  for (int rr = 0; rr < ROWS; rr++){
    const float* Ar = A + (size_t)(rowbase + rr) * N;
    #pragma unroll
    for (int q = 0; q < 4; q++){
      int c = (q * NTHR + tid) * 4;
      float4 a = ld4(Ar + c);
      Af[rr][2*q]   = __floats2half2_rn(a.x, a.y);
      Af[rr][2*q+1] = __floats2half2_rn(a.z, a.w);
    }
  }

  float4 ysbf[4], ysf[4];              // base / stage vector fragments (fp32)
  #pragma unroll
  for (int q = 0; q < 4; q++) ysbf[q] = ld4(x + (q * NTHR + tid) * 4);
  __syncthreads();

  const float t_end = (float)(*tptr);
  const float Tf    = (float)Tm;
  float t = 0.0f;
  float h = t_end * 0.01f;
  unsigned gen = 0;

  // matvec from registers: acc over our 16 cols, wave-reduce, park in part_sm
  auto mv = [&](){
    float acc[ROWS];
    #pragma unroll
    for (int rr = 0; rr < ROWS; rr++) acc[rr] = 0.0f;
    #pragma unroll
    for (int q = 0; q < 4; q++){
      float4 y = ysf[q];
      #pragma unroll
      for (int rr = 0; rr < ROWS; rr++){
        float2 lo = __half22float2(Af[rr][2*q]);
        float2 hi = __half22float2(Af[rr][2*q+1]);
        acc[rr] = fmaf(lo.x, y.x, fmaf(lo.y, y.y, fmaf(hi.x, y.z, fmaf(hi.y, y.w, acc[rr]))));
      }
    }
    __syncthreads();                   // part_sm free from previous stage
    #pragma unroll
    for (int rr = 0; rr < ROWS; rr++){
      float s = acc[rr];
      #pragma unroll
      for (int off = 32; off; off >>= 1) s += __shfl_xor(s, off, 64);
      if (lane == 0) part_sm[rr * 4 + wv] = s;
    }
    __syncthreads();
  };

  // k for row `tid` (tid<ROWS): y_s * (r + A@y_s + eps@P[d])
  auto kval = [&](float ts) -> float {
    int d = (int)((Tf * ts) / 30.0f);
    d = d < 0 ? 0 : (d > Tm ? Tm : d);
    float dot = part_sm[tid*4] + part_sm[tid*4+1] + part_sm[tid*4+2] + part_sm[tid*4+3];
    float ep = 0.f;
    #pragma unroll
    for (int p = 0; p < PERTS; p++) ep += eps_sh[tid * PERTS + p] * P_sh[d * PERTS + p];
    return ys_rows[tid] * (r_sh[tid] + dot + ep);
  };

  // ys = ysb + h * sum(cf[m] * khist[sli[m]]) over our 16 columns
  auto build = [&](const int* sli, const float* cf, int nk){
    #pragma unroll
    for (int q = 0; q < 4; q++){
      int c = (q * NTHR + tid) * 4;
      float4 v = ysbf[q];
      for (int m = 0; m < nk; m++){
        float cc = h * cf[m];
        float4 kv = ld4(&khist[sli[m]][c]);
        v.x = fmaf(cc, kv.x, v.x); v.y = fmaf(cc, kv.y, v.y);
        v.z = fmaf(cc, kv.z, v.z); v.w = fmaf(cc, kv.w, v.w);
      }
      ysf[q] = v;
      int o = c - rowbase;             // c,rowbase multiples of 4/16: full containment
      if (o >= 0 && o < ROWS) st4(&ys_rows[o], v);
    }
    __syncthreads();
  };

  // publish own 16 k's (agent atomics), fence-free barrier, pull 4096 into khist[slot]
  auto exchange = [&](int slot, float kv){
    ++gen;
    ull* kx = (gen & 1u) ? kx1u : kx0u;          // double buffer by parity
    if (wv == 0){
      float kvn = __shfl_down(kv, 1, 64);
      if ((lane & 1) == 0 && lane < ROWS){
        union { float2 f; ull u; } cv;
        cv.f = make_float2(kv, kvn);
        __hip_atomic_store(&kx[(rowbase >> 1) + (lane >> 1)], cv.u,
                           __ATOMIC_RELAXED, __HIP_MEMORY_SCOPE_AGENT);
      }
    }
    __syncthreads();                             // all work for this stage done
    if (tid == 0){
      __builtin_amdgcn_sched_barrier(0);
      __builtin_amdgcn_s_waitcnt(0);             // kx/err stores at coherence point
      __builtin_amdgcn_sched_barrier(0);
      __hip_atomic_store(&flags[b], gen, __ATOMIC_RELAXED, __HIP_MEMORY_SCOPE_AGENT);
    }
    if (wv == 0){                                // wave 0 polls all 256 flags
      for (;;){
        bool ok = true;
        #pragma unroll
        for (int j = 0; j < 4; j++){
          unsigned f = __hip_atomic_load(&flags[j * 64 + lane],
                                         __ATOMIC_RELAXED, __HIP_MEMORY_SCOPE_AGENT);
          ok = ok && (f >= gen);
        }
        if (__all(ok)) break;
        __builtin_amdgcn_s_sleep(2);
      }
    }
    __syncthreads();
    float2* kh2 = reinterpret_cast<float2*>(&khist[slot][0]);
    #pragma unroll
    for (int i = 0; i < 8; i++){                 // coalesced dwordx2 atomic loads
      union { float2 f; ull u; } cv;
      cv.u = __hip_atomic_load(&kx[i * NTHR + tid], __ATOMIC_RELAXED, __HIP_MEMORY_SCOPE_AGENT);
      kh2[i * NTHR + tid] = cv.f;
    }
    __syncthreads();
  };

  // deterministic redundant reduce of the 256 per-block err partials
  auto read_err = [&]() -> float {
    if (tid < 64){
      float e = 0.f;
      #pragma unroll
      for (int j = 0; j < 4; j++)
        e += __hip_atomic_load(&err_part[tid + j * 64],
                               __ATOMIC_RELAXED, __HIP_MEMORY_SCOPE_AGENT);
      #pragma unroll
      for (int off = 32; off; off >>= 1) e += __shfl_xor(e, off, 64);
      if (tid == 0) es_sh = e;
    }
    __syncthreads();
    float v = es_sh;
    __syncthreads();
    return v;
  };

  int sl[6] = {0, 1, 2, 3, 4, 5};      // logical k1..k6 -> physical LDS slots
  bool exhausted = true;

  for (int n = 0; n < MAXSTEP; ++n){
    if (n > 0){
      float es = read_err();
      float enorm = sqrtf(es * (1.0f / (float)N));
      bool accept = (enorm <= 1.0f);
      if (accept){
        t += h;
        int tmp = sl[0]; sl[0] = sl[1]; sl[1] = tmp;  // FSAL: k1 <- k7 (in k2's slot)
        #pragma unroll
        for (int q = 0; q < 4; q++) ysbf[q] = ysf[q];
        if (tid < ROWS) ysb_rows[tid] = ys_rows[tid];
      }
      float fac = 0.9f * powf(enorm + 1e-10f, -0.2f);
      fac = fminf(fmaxf(fac, 0.2f), 10.0f);
      h *= fac;
      __syncthreads();
    }
    if (t >= t_end) { exhausted = false; break; }
    h = fminf(h, t_end - t);
    if (!(h > 0.0f)) { exhausted = false; break; }

    if (n == 0){
      // ---- stage 1 (once ever; FSAL covers later steps) ----
      #pragma unroll
      for (int q = 0; q < 4; q++){
        ysf[q] = ysbf[q];
        int c = (q * NTHR + tid) * 4, o = c - rowbase;
        if (o >= 0 && o < ROWS) st4(&ys_rows[o], ysf[q]);
      }
      __syncthreads();
      mv();
      float kv = (tid < ROWS) ? kval(t) : 0.f;
      exchange(sl[0], kv);
    }

    // ---- stage 2 ----
    { const float cf[1] = {0.2f}; const int s_[1] = {sl[0]};
      build(s_, cf, 1); mv();
      float kv = (tid < ROWS) ? kval(t + 0.2f * h) : 0.f;
      exchange(sl[1], kv); }

    // ---- stage 3 ----
    { const float cf[2] = {3.f/40.f, 9.f/40.f}; const int s_[2] = {sl[0], sl[1]};
      build(s_, cf, 2); mv();
      float kv = (tid < ROWS) ? kval(t + 0.3f * h) : 0.f;
      exchange(sl[2], kv); }

    // ---- stage 4 ----
    { const float cf[3] = {44.f/45.f, -56.f/15.f, 32.f/9.f};
      const int s_[3] = {sl[0], sl[1], sl[2]};
      build(s_, cf, 3); mv();
      float kv = (tid < ROWS) ? kval(t + 0.8f * h) : 0.f;
      exchange(sl[3], kv); }

    // ---- stage 5 ----
    { const float cf[4] = {19372.f/6561.f, -25360.f/2187.f, 64448.f/6561.f, -212.f/729.f};
      const int s_[4] = {sl[0], sl[1], sl[2], sl[3]};
      build(s_, cf, 4); mv();
      float kv = (tid < ROWS) ? kval(t + (8.f/9.f) * h) : 0.f;
      exchange(sl[4], kv); }

    // ---- stage 6 ----
    { const float cf[5] = {9017.f/3168.f, -355.f/33.f, 46732.f/5247.f, 49.f/176.f, -5103.f/18656.f};
      const int s_[5] = {sl[0], sl[1], sl[2], sl[3], sl[4]};
      build(s_, cf, 5); mv();
      float kv = (tid < ROWS) ? kval(t + h) : 0.f;
      exchange(sl[5], kv); }

    // ---- stage 7: ys = y5 candidate; err partial; k7 -> sl[1] (k2 dead) ----
    { const float cf[5] = {35.f/384.f, 500.f/1113.f, 125.f/192.f, -2187.f/6784.f, 11.f/84.f};
      const int s_[5] = {sl[0], sl[2], sl[3], sl[4], sl[5]};
      build(s_, cf, 5);                // ys == y5 candidate; ys_rows updated
      mv();
      float k7v = 0.f;
      if (tid < ROWS){
        k7v = kval(t + h);
        int gi = rowbase + tid;
        float e = (71.f/57600.f)  * khist[sl[0]][gi] - (71.f/16695.f)    * khist[sl[2]][gi]
                + (71.f/1920.f)   * khist[sl[3]][gi] - (17253.f/339200.f)* khist[sl[4]][gi]
                + (22.f/525.f)    * khist[sl[5]][gi] - (1.f/40.f)        * k7v;
        e *= h;
        float sc = 1e-6f + 1e-3f * fmaxf(fabsf(ysb_rows[tid]), fabsf(ys_rows[tid]));
        float q = e / sc;
        epr_sh[tid] = q * q;
      }
      __syncthreads();
      if (tid == 0){
        float s = 0.f;
        #pragma unroll
        for (int i = 0; i < ROWS; i++) s += epr_sh[i];
        __hip_atomic_store(&err_part[b], s, __ATOMIC_RELAXED, __HIP_MEMORY_SCOPE_AGENT);
      }
      exchange(sl[1], k7v);            // barrier also orders/publishes err_part
    }
  }

  if (exhausted){
    // apply the final (iteration 511) accept decision, as the reference does
    float es = read_err();
    bool accept = sqrtf(es * (1.0f / (float)N)) <= 1.0f;
    if (tid < ROWS) out[rowbase + tid] = accept ? ys_rows[tid] : ysb_rows[tid];
  } else {
    if (tid < ROWS) out[rowbase + tid] = ysb_rows[tid];
  }
}

extern "C" void kernel_launch(void* const* d_in, const int* in_sizes, int n_in,
                              void* d_out, int out_size, void* d_ws, size_t ws_size,
                              hipStream_t stream)
{
  const float* x   = (const float*)d_in[0];
  const int*   tp  = (const int*)  d_in[1];
  const float* r   = (const float*)d_in[2];
  const float* A   = (const float*)d_in[3];
  const float* eps = (const float*)d_in[4];
  const float* Pm  = (const float*)d_in[5];
  float* out = (float*)d_out;
  float* W   = (float*)d_ws;
  int Tm = in_sizes[5] / PERTS - 1;   // P rows - 1  (== 30)

  // zero the barrier flag array (everything else is written before read)
  hipMemsetAsync(d_ws, 0, 1024, stream);
  mbpert_rk45_kernel<<<dim3(NBLK), dim3(NTHR), 0, stream>>>(
      x, tp, r, A, eps, Pm, out, W, Tm);
}

// Round 7
// 13573.836 us; speedup vs baseline: 5.0712x; 1.2332x over previous
//
#include <hip/hip_runtime.h>
#include <hip/hip_fp16.h>
#include <math.h>

// Persistent RK45 (Dormand-Prince, FSAL) integrator for
//   dy/dt = y * (r + A@y + eps@P[d(t)]),  n=4096, up to 512 adaptive steps.
// R7: centralized two-phase barrier, R5-proven primitives only.
// R5 analysis (revised): the ~21us/stage overhead was POLL congestion --
// 256 blocks x 64 lanes x 4 flag loads re-issued every ~200cyc = 65K
// uncached coherence-point loads per sweep. Now only block 0 scans the 256
// flags, reduces the err partials (same order as R5 -> bitwise-identical
// trajectory), and publishes ONE packed (gen,err) 8-byte word; the other
// 255 blocks poll that single word (1 load/sweep each). Poll traffic -100x.
// R6's XCC_ID / sc0-asm / L2-mirror experiment hung the harness -- all
// reverted; every cross-block primitive here is exactly what R5 validated.
// A stays permanently in registers as fp16 (zero steady-state HBM traffic).

#define N        4096
#define NBLK     256
#define NTHR     256
#define ROWS     16          // rows of A per block (NBLK*ROWS == N)
#define MAXSTEP  512
#define PERTS    8

typedef unsigned long long ull;

static_assert(NBLK * ROWS == N, "row partition");
static_assert(NTHR * 16 == N, "column partition (4 float4 per thread)");

__device__ __forceinline__ float4 ld4(const float* p){ return *reinterpret_cast<const float4*>(p); }
__device__ __forceinline__ void   st4(float* p, float4 v){ *reinterpret_cast<float4*>(p) = v; }

__global__ void __launch_bounds__(NTHR, 1)
mbpert_rk45_kernel(const float* __restrict__ x, const int* __restrict__ tptr,
                   const float* __restrict__ r, const float* __restrict__ A,
                   const float* __restrict__ eps, const float* __restrict__ Pm,
                   float* __restrict__ out, float* __restrict__ W, int Tm)
{
  __shared__ float khist[6][N];        // 96 KB k-history (gfx950: 160KB LDS/WG)
  __shared__ float part_sm[ROWS * 4];  // per-wave matvec partials
  __shared__ float ys_rows[ROWS];      // stage vector at our 16 row indices
  __shared__ float ysb_rows[ROWS];     // base vector at our 16 row indices
  __shared__ float r_sh[ROWS];
  __shared__ float eps_sh[ROWS * PERTS];
  __shared__ float P_sh[32 * PERTS];
  __shared__ float epr_sh[ROWS];
  __shared__ float es_sh;

  const int tid = threadIdx.x;
  const int b   = blockIdx.x;
  const int rowbase = b * ROWS;
  const int lane = tid & 63;
  const int wv   = tid >> 6;

  unsigned* flags    = reinterpret_cast<unsigned*>(W);       // [256] per-block stage flags
  float*    err_part = W + 256;                              // [256] err partials
  ull*      bword    = reinterpret_cast<ull*>(W + 512);      // packed (gen<<32 | err bits)
  ull*      kx0u     = reinterpret_cast<ull*>(W + 1024);     // [N/2] exchange buf A
  ull*      kx1u     = reinterpret_cast<ull*>(W + 1024 + N); // [N/2] exchange buf B

  // ---- persistent LDS constants ----
  if (tid < ROWS)             r_sh[tid]   = r[rowbase + tid];
  if (tid < ROWS * PERTS)     eps_sh[tid] = eps[rowbase * PERTS + tid];
  if (tid < (Tm + 1) * PERTS) P_sh[tid]   = Pm[tid];
  if (tid < ROWS)             ysb_rows[tid] = x[rowbase + tid];

  // ---- A fragment -> registers (fp16), once ----
  // Thread owns cols (q*256+tid)*4..+3 (q=0..3) of rows rowbase..rowbase+15.
  __half2 Af[ROWS][8];
  #pragma unroll
  for (int rr = 0; rr < ROWS; rr++){
    const float* Ar = A + (size_t)(rowbase + rr) * N;
    #pragma unroll
    for (int q = 0; q < 4; q++){
      int c = (q * NTHR + tid) * 4;
      float4 a = ld4(Ar + c);
      Af[rr][2*q]   = __floats2half2_rn(a.x, a.y);
      Af[rr][2*q+1] = __floats2half2_rn(a.z, a.w);
    }
  }

  float4 ysbf[4], ysf[4];              // base / stage vector fragments (fp32)
  #pragma unroll
  for (int q = 0; q < 4; q++) ysbf[q] = ld4(x + (q * NTHR + tid) * 4);
  __syncthreads();

  const float t_end = (float)(*tptr);
  const float Tf    = (float)Tm;
  float t = 0.0f;
  float h = t_end * 0.01f;
  unsigned gen = 0;

  // matvec from registers: acc over our 16 cols, wave-reduce, park in part_sm
  auto mv = [&](){
    float acc[ROWS];
    #pragma unroll
    for (int rr = 0; rr < ROWS; rr++) acc[rr] = 0.0f;
    #pragma unroll
    for (int q = 0; q < 4; q++){
      float4 y = ysf[q];
      #pragma unroll
      for (int rr = 0; rr < ROWS; rr++){
        float2 lo = __half22float2(Af[rr][2*q]);
        float2 hi = __half22float2(Af[rr][2*q+1]);
        acc[rr] = fmaf(lo.x, y.x, fmaf(lo.y, y.y, fmaf(hi.x, y.z, fmaf(hi.y, y.w, acc[rr]))));
      }
    }
    __syncthreads();                   // part_sm free from previous stage
    #pragma unroll
    for (int rr = 0; rr < ROWS; rr++){
      float s = acc[rr];
      #pragma unroll
      for (int off = 32; off; off >>= 1) s += __shfl_xor(s, off, 64);
      if (lane == 0) part_sm[rr * 4 + wv] = s;
    }
    __syncthreads();
  };

  // k for row `tid` (tid<ROWS): y_s * (r + A@y_s + eps@P[d])
  auto kval = [&](float ts) -> float {
    int d = (int)((Tf * ts) / 30.0f);
    d = d < 0 ? 0 : (d > Tm ? Tm : d);
    float dot = part_sm[tid*4] + part_sm[tid*4+1] + part_sm[tid*4+2] + part_sm[tid*4+3];
    float ep = 0.f;
    #pragma unroll
    for (int p = 0; p < PERTS; p++) ep += eps_sh[tid * PERTS + p] * P_sh[d * PERTS + p];
    return ys_rows[tid] * (r_sh[tid] + dot + ep);
  };

  // ys = ysb + h * sum(cf[m] * khist[sli[m]]) over our 16 columns
  auto build = [&](const int* sli, const float* cf, int nk){
    #pragma unroll
    for (int q = 0; q < 4; q++){
      int c = (q * NTHR + tid) * 4;
      float4 v = ysbf[q];
      for (int m = 0; m < nk; m++){
        float cc = h * cf[m];
        float4 kv = ld4(&khist[sli[m]][c]);
        v.x = fmaf(cc, kv.x, v.x); v.y = fmaf(cc, kv.y, v.y);
        v.z = fmaf(cc, kv.z, v.z); v.w = fmaf(cc, kv.w, v.w);
      }
      ysf[q] = v;
      int o = c - rowbase;             // c,rowbase multiples of 4/16: full containment
      if (o >= 0 && o < ROWS) st4(&ys_rows[o], v);
    }
    __syncthreads();
  };

  // publish own 16 k's (+err), two-phase barrier via block 0, pull 4096 into khist[slot]
  auto exchange = [&](int slot, float kv, bool werr, float errv){
    ++gen;
    ull* kx = (gen & 1u) ? kx1u : kx0u;          // double buffer by parity
    if (wv == 0){
      float kvn = __shfl_down(kv, 1, 64);
      if ((lane & 1) == 0 && lane < ROWS){
        union { float2 f; ull u; } cv;
        cv.f = make_float2(kv, kvn);
        __hip_atomic_store(&kx[(rowbase >> 1) + (lane >> 1)], cv.u,
                           __ATOMIC_RELAXED, __HIP_MEMORY_SCOPE_AGENT);
      }
      if (werr && lane == 0)
        __hip_atomic_store(&err_part[b], errv, __ATOMIC_RELAXED, __HIP_MEMORY_SCOPE_AGENT);
    }
    __syncthreads();                             // all stage work done
    if (tid == 0){
      __builtin_amdgcn_sched_barrier(0);
      __builtin_amdgcn_s_waitcnt(0);             // kx/err stores at coherence point
      __builtin_amdgcn_sched_barrier(0);
      __hip_atomic_store(&flags[b], gen, __ATOMIC_RELAXED, __HIP_MEMORY_SCOPE_AGENT);
    }
    if (b == 0){
      // ---- aggregator: scan all 256 flags, then broadcast one packed word ----
      if (wv == 0){
        for (;;){
          bool ok = true;
          #pragma unroll
          for (int j = 0; j < 4; j++){
            unsigned f = __hip_atomic_load(&flags[j * 64 + lane],
                                           __ATOMIC_RELAXED, __HIP_MEMORY_SCOPE_AGENT);
            ok = ok && (f >= gen);
          }
          if (__all(ok)) break;
          __builtin_amdgcn_s_sleep(2);
        }
        float es = 0.f;
        if (werr){                               // same order as R5 read_err -> bitwise identical
          #pragma unroll
          for (int j = 0; j < 4; j++)
            es += __hip_atomic_load(&err_part[lane + j * 64],
                                    __ATOMIC_RELAXED, __HIP_MEMORY_SCOPE_AGENT);
          #pragma unroll
          for (int off = 32; off; off >>= 1) es += __shfl_xor(es, off, 64);
        }
        if (lane == 0){
          if (werr) es_sh = es;
          ull pk = ((ull)gen << 32) | (ull)__float_as_uint(es);
          __builtin_amdgcn_sched_barrier(0);
          __builtin_amdgcn_s_waitcnt(0);
          __builtin_amdgcn_sched_barrier(0);
          __hip_atomic_store(bword, pk, __ATOMIC_RELAXED, __HIP_MEMORY_SCOPE_AGENT);
        }
      }
      __syncthreads();
    } else {
      // ---- follower: poll the single broadcast word ----
      if (tid == 0){
        for (;;){
          ull w = __hip_atomic_load(bword, __ATOMIC_RELAXED, __HIP_MEMORY_SCOPE_AGENT);
          if ((unsigned)(w >> 32) >= gen){
            if (werr) es_sh = __uint_as_float((unsigned)(w & 0xffffffffu));
            break;
          }
          __builtin_amdgcn_s_sleep(2);
        }
      }
      __syncthreads();
    }
    // ---- all blocks: pull the full k-vector ----
    float2* kh2 = reinterpret_cast<float2*>(&khist[slot][0]);
    #pragma unroll
    for (int i = 0; i < 8; i++){                 // coalesced dwordx2 atomic loads
      union { float2 f; ull u; } cv;
      cv.u = __hip_atomic_load(&kx[i * NTHR + tid], __ATOMIC_RELAXED, __HIP_MEMORY_SCOPE_AGENT);
      kh2[i * NTHR + tid] = cv.f;
    }
    __syncthreads();
  };

  int sl[6] = {0, 1, 2, 3, 4, 5};      // logical k1..k6 -> physical LDS slots
  bool exhausted = true;

  for (int n = 0; n < MAXSTEP; ++n){
    if (n > 0){
      float es = es_sh;                          // set by last stage-7 exchange
      float enorm = sqrtf(es * (1.0f / (float)N));
      bool accept = (enorm <= 1.0f);
      if (accept){
        t += h;
        int tmp = sl[0]; sl[0] = sl[1]; sl[1] = tmp;  // FSAL: k1 <- k7 (in k2's slot)
        #pragma unroll
        for (int q = 0; q < 4; q++) ysbf[q] = ysf[q];
        if (tid < ROWS) ysb_rows[tid] = ys_rows[tid];
      }
      float fac = 0.9f * powf(enorm + 1e-10f, -0.2f);
      fac = fminf(fmaxf(fac, 0.2f), 10.0f);
      h *= fac;
      __syncthreads();
    }
    if (t >= t_end) { exhausted = false; break; }
    h = fminf(h, t_end - t);
    if (!(h > 0.0f)) { exhausted = false; break; }

    if (n == 0){
      // ---- stage 1 (once ever; FSAL covers later steps) ----
      #pragma unroll
      for (int q = 0; q < 4; q++){
        ysf[q] = ysbf[q];
        int c = (q * NTHR + tid) * 4, o = c - rowbase;
        if (o >= 0 && o < ROWS) st4(&ys_rows[o], ysf[q]);
      }
      __syncthreads();
      mv();
      float kv = (tid < ROWS) ? kval(t) : 0.f;
      exchange(sl[0], kv, false, 0.f);
    }

    // ---- stage 2 ----
    { const float cf[1] = {0.2f}; const int s_[1] = {sl[0]};
      build(s_, cf, 1); mv();
      float kv = (tid < ROWS) ? kval(t + 0.2f * h) : 0.f;
      exchange(sl[1], kv, false, 0.f); }

    // ---- stage 3 ----
    { const float cf[2] = {3.f/40.f, 9.f/40.f}; const int s_[2] = {sl[0], sl[1]};
      build(s_, cf, 2); mv();
      float kv = (tid < ROWS) ? kval(t + 0.3f * h) : 0.f;
      exchange(sl[2], kv, false, 0.f); }

    // ---- stage 4 ----
    { const float cf[3] = {44.f/45.f, -56.f/15.f, 32.f/9.f};
      const int s_[3] = {sl[0], sl[1], sl[2]};
      build(s_, cf, 3); mv();
      float kv = (tid < ROWS) ? kval(t + 0.8f * h) : 0.f;
      exchange(sl[3], kv, false, 0.f); }

    // ---- stage 5 ----
    { const float cf[4] = {19372.f/6561.f, -25360.f/2187.f, 64448.f/6561.f, -212.f/729.f};
      const int s_[4] = {sl[0], sl[1], sl[2], sl[3]};
      build(s_, cf, 4); mv();
      float kv = (tid < ROWS) ? kval(t + (8.f/9.f) * h) : 0.f;
      exchange(sl[4], kv, false, 0.f); }

    // ---- stage 6 ----
    { const float cf[5] = {9017.f/3168.f, -355.f/33.f, 46732.f/5247.f, 49.f/176.f, -5103.f/18656.f};
      const int s_[5] = {sl[0], sl[1], sl[2], sl[3], sl[4]};
      build(s_, cf, 5); mv();
      float kv = (tid < ROWS) ? kval(t + h) : 0.f;
      exchange(sl[5], kv, false, 0.f); }

    // ---- stage 7: ys = y5 candidate; err partial; k7 -> sl[1] (k2 dead) ----
    { const float cf[5] = {35.f/384.f, 500.f/1113.f, 125.f/192.f, -2187.f/6784.f, 11.f/84.f};
      const int s_[5] = {sl[0], sl[2], sl[3], sl[4], sl[5]};
      build(s_, cf, 5);                // ys == y5 candidate; ys_rows updated
      mv();
      float k7v = 0.f, errv = 0.f;
      if (tid < ROWS){
        k7v = kval(t + h);
        int gi = rowbase + tid;
        float e = (71.f/57600.f)  * khist[sl[0]][gi] - (71.f/16695.f)    * khist[sl[2]][gi]
                + (71.f/1920.f)   * khist[sl[3]][gi] - (17253.f/339200.f)* khist[sl[4]][gi]
                + (22.f/525.f)    * khist[sl[5]][gi] - (1.f/40.f)        * k7v;
        e *= h;
        float sc = 1e-6f + 1e-3f * fmaxf(fabsf(ysb_rows[tid]), fabsf(ys_rows[tid]));
        float q = e / sc;
        epr_sh[tid] = q * q;
      }
      __syncthreads();
      if (tid == 0){
        float s = 0.f;
        #pragma unroll
        for (int i = 0; i < ROWS; i++) s += epr_sh[i];
        errv = s;
      }
      exchange(sl[1], k7v, true, errv);          // barrier + err broadcast + k7 fetch
    }
  }

  if (exhausted){
    // apply the final (iteration 511) accept decision, as the reference does
    float es = es_sh;
    bool accept = sqrtf(es * (1.0f / (float)N)) <= 1.0f;
    if (tid < ROWS) out[rowbase + tid] = accept ? ys_rows[tid] : ysb_rows[tid];
  } else {
    if (tid < ROWS) out[rowbase + tid] = ysb_rows[tid];
  }
}

extern "C" void kernel_launch(void* const* d_in, const int* in_sizes, int n_in,
                              void* d_out, int out_size, void* d_ws, size_t ws_size,
                              hipStream_t stream)
{
  const float* x   = (const float*)d_in[0];
  const int*   tp  = (const int*)  d_in[1];
  const float* r   = (const float*)d_in[2];
  const float* A   = (const float*)d_in[3];
  const float* eps = (const float*)d_in[4];
  const float* Pm  = (const float*)d_in[5];
  float* out = (float*)d_out;
  float* W   = (float*)d_ws;
  int Tm = in_sizes[5] / PERTS - 1;   // P rows - 1  (== 30)

  // zero flags / err partials / broadcast word (ws re-poisoned per call)
  hipMemsetAsync(d_ws, 0, 4096, stream);
  mbpert_rk45_kernel<<<dim3(NBLK), dim3(NTHR), 0, stream>>>(
      x, tp, r, A, eps, Pm, out, W, Tm);
}